// Round 7
// baseline (579.868 us; speedup 1.0000x reference)
//
#include <hip/hip_runtime.h>

// SlotAttention fused implementation (f32 hln, row-major).
//   - 6-layer linear stack folded into effective 66->128 affine (Wh, bh).
//   - k,v projections folded out of the N dimension:
//       q.k_n = (wk@q) . hln_n + q.bk ;  updates = (sum attn*hln)/den @ wv + bv
//   - hln = LN(h) f32 row-major [NB][128].
//   - slot init: JAX partitionable threefry: bits[i] = o0^o1, counter (0,i).
//   - k2: 64 rows/block, thread = 8 rows x 4 cols register tile.
//   - k4: 1024 blocks x 4 tiles(64 rows), LDS 40.1KB -> 4 blocks/CU.
//   - k0: transposes gru wih/whh and wk for coalesced k5/emit_q reads.

#define B_  8
#define N_  32768
#define NB_ (B_ * N_)   // 262144 rows
#define D_  128
#define S_  8

typedef unsigned int u32;

// threefry2x32, key = (0, 42)  (jax.random.key(42))
__device__ inline void threefry42(u32 c0, u32 c1, u32& o0, u32& o1) {
    const u32 k0 = 0u, k1 = 42u, k2 = 0x1BD11BDAu ^ 0u ^ 42u;
    const u32 ks[3] = {k0, k1, k2};
    u32 x0 = c0 + k0, x1 = c1 + k1;
    const int rA[4] = {13, 15, 26, 6}, rB[4] = {17, 29, 16, 24};
#pragma unroll
    for (int i = 0; i < 5; i++) {
#pragma unroll
        for (int k = 0; k < 4; k++) {
            int r = (i & 1) ? rB[k] : rA[k];
            x0 += x1;
            x1 = (x1 << r) | (x1 >> (32 - r));
            x1 ^= x0;
        }
        x0 += ks[(i + 1) % 3];
        x1 += ks[(i + 2) % 3] + (u32)(i + 1);
    }
    o0 = x0; o1 = x1;
}

// jax uniform(-0.99999994, 1) -> sqrt(2)*erfinv  (XLA ErfInv32 polynomial)
__device__ inline float bits_to_normal(u32 b) {
    float f = __uint_as_float((b >> 9) | 0x3f800000u) - 1.0f;  // [0,1)
    const float lo = -0.99999994f;
    float r = fmaxf(lo, f * 1.99999994f + lo);
    float w = -log1pf(-r * r);
    float p;
    if (w < 5.0f) {
        w -= 2.5f;
        p = 2.81022636e-08f;
        p = fmaf(p, w, 3.43273939e-07f);
        p = fmaf(p, w, -3.5233877e-06f);
        p = fmaf(p, w, -4.39150654e-06f);
        p = fmaf(p, w, 0.00021858087f);
        p = fmaf(p, w, -0.00125372503f);
        p = fmaf(p, w, -0.00417768164f);
        p = fmaf(p, w, 0.246640727f);
        p = fmaf(p, w, 1.50140941f);
    } else {
        w = sqrtf(w) - 3.0f;
        p = -0.000200214257f;
        p = fmaf(p, w, 0.000100950558f);
        p = fmaf(p, w, 0.00134934322f);
        p = fmaf(p, w, -0.00367342844f);
        p = fmaf(p, w, 0.00573950773f);
        p = fmaf(p, w, -0.0076224613f);
        p = fmaf(p, w, 0.00943887047f);
        p = fmaf(p, w, 1.00167406f);
        p = fmaf(p, w, 2.83297682f);
    }
    return 1.41421356f * (p * r);
}

// 128-thread block sum (2 waves), red = 2-float shared scratch
__device__ inline float block128_sum(float v, float* red) {
#pragma unroll
    for (int o = 32; o; o >>= 1) v += __shfl_down(v, o);
    __syncthreads();
    if ((threadIdx.x & 63) == 0) red[threadIdx.x >> 6] = v;
    __syncthreads();
    return red[0] + red[1];
}

// LN(slot row) -> q -> qtilde(scaled), qc(scaled); zero vec/den accumulators.
// wkT is wk transposed: wkT[j*128+t] = wk[t*128+j]  (coalesced loop reads).
__device__ void emit_q(float x, int bs,
                       const float* lnsg, const float* lnsb,
                       const float* wq, const float* bq,
                       const float* wkT, const float* bk,
                       float* qt, float* qc, float* vec, float* den,
                       float* shA, float* red) {
    int t = threadIdx.x;
    float m = block128_sum(x, red) * (1.0f / 128.0f);
    float e = x - m;
    float var = block128_sum(e * e, red) * (1.0f / 128.0f);
    float inv = rsqrtf(var + 1e-5f);
    __syncthreads();
    shA[t] = fmaf(e * inv, lnsg[t], lnsb[t]);
    __syncthreads();
    float q = bq[t];
#pragma unroll 4
    for (int i = 0; i < 128; i++) q = fmaf(shA[i], wq[i * 128 + t], q);
    __syncthreads();
    shA[t] = q;
    __syncthreads();
    float a2 = 0.f;
#pragma unroll 4
    for (int j = 0; j < 128; j++) a2 = fmaf(wkT[j * 128 + t], shA[j], a2);
    const float scale = 0.08838834764831845f;  // 128^-0.5
    qt[bs * 128 + t] = a2 * scale;
    float pr = block128_sum(shA[t] * bk[t], red);
    if (t == 0) { qc[bs] = pr * scale; den[bs] = 0.f; }
    vec[bs * 128 + t] = 0.f;
}

// ---------- K0: transpose gru weights + wk for coalesced access ----------

__global__ __launch_bounds__(256) void k0_transpose(
    const float* __restrict__ wih, const float* __restrict__ whh,
    const float* __restrict__ wk,
    float* __restrict__ wihT, float* __restrict__ whhT, float* __restrict__ wkT) {
    int idx = blockIdx.x * 256 + threadIdx.x;
    if (idx < 49152) {
        int d = idx / 384, g = idx % 384;
        wihT[idx] = wih[g * 128 + d];
    } else if (idx < 98304) {
        int o = idx - 49152;
        int d = o / 384, g = o % 384;
        whhT[o] = whh[g * 128 + d];
    } else if (idx < 114688) {
        int o = idx - 98304;
        int j = o >> 7, tcol = o & 127;
        wkT[o] = wk[tcol * 128 + j];
    }
}

// ---------- K1: fold weights, init slots ----------

__global__ __launch_bounds__(256) void k1_setup(
    const float* __restrict__ w0, const float* __restrict__ b0,
    const float* __restrict__ w1, const float* __restrict__ b1,
    const float* __restrict__ w2, const float* __restrict__ b2,
    const float* __restrict__ w3, const float* __restrict__ b3,
    const float* __restrict__ w4, const float* __restrict__ b4,
    const float* __restrict__ w5, const float* __restrict__ b5,
    const float* __restrict__ w7, const float* __restrict__ b7,
    const float* __restrict__ mu, const float* __restrict__ sg,
    float* __restrict__ Wh, float* __restrict__ bh, float* __restrict__ slots) {
    __shared__ float A[192], Bt[96], bb[64], bb2[32];
    __shared__ float stats[2];
    int t = threadIdx.x;
    for (int i = t; i < 192; i += 256) A[i] = w0[i];
    for (int i = t; i < 64; i += 256) bb[i] = b0[i];
    __syncthreads();
    const float* wl[5] = {w1, w2, w3, w4, w5};
    const float* bl[5] = {b1, b2, b3, b4, b5};
    int kin = 64;
    for (int l = 0; l < 5; l++) {
        const float* w = wl[l];
        const float* bias = bl[l];
        if (t < 96) {
            int i = t / 32, j = t % 32;
            float acc = 0.f;
            for (int k = 0; k < kin; k++) acc += A[i * kin + k] * w[k * 32 + j];
            Bt[i * 32 + j] = acc;
        } else if (t < 128) {
            int j = t - 96;
            float acc = bias[j];
            for (int k = 0; k < kin; k++) acc += bb[k] * w[k * 32 + j];
            bb2[j] = acc;
        }
        __syncthreads();
        if (t < 96) A[t] = Bt[t];
        if (t < 32) bb[t] = bb2[t];
        __syncthreads();
        kin = 32;
    }
    for (int idx = t; idx < 66 * 128; idx += 256) {
        int i = idx >> 7, j = idx & 127;
        float acc = w7[idx];
        if (i < 3) {
            for (int k = 0; k < 32; k++) acc += A[i * 32 + k] * w7[(66 + k) * 128 + j];
        }
        Wh[idx] = acc;
    }
    for (int j = t; j < 128; j += 256) {
        float acc = b7[j];
        for (int k = 0; k < 32; k++) acc += bb[k] * w7[(66 + k) * 128 + j];
        bh[j] = acc;
    }
    if (t == 0) {
        float s1 = 0.f, s2 = 0.f;
        for (int d = 0; d < 128; d++) { s1 += mu[d]; s2 += sg[d]; }
        float mmu = s1 / 128.f, msg = s2 / 128.f;
        float ss = 0.f;
        for (int d = 0; d < 128; d++) { float e = sg[d] - msg; ss += e * e; }
        stats[0] = mmu;
        stats[1] = sqrtf(64.f * ss / 8191.f);  // std over broadcast 8192, ddof=1
    }
    __syncthreads();
    float mean = stats[0], sd = stats[1];
    for (int p = t; p < 8192; p += 256) {
        u32 o0, o1;
        threefry42(0u, (u32)p, o0, o1);
        slots[p] = fmaf(sd, bits_to_normal(o0 ^ o1), mean);
    }
}

// ---------- K2: build hln (f32 row-major [NB][128]) ----------
// 64 rows/block; thread (tr 0-7, tc 0-31) owns rows tr*8..+7, cols tc*4..+3.

__global__ __launch_bounds__(256) void k2_hln(
    const float* __restrict__ inputs, const float* __restrict__ embed,
    const float* __restrict__ Wh, const float* __restrict__ bh,
    const float* __restrict__ g, const float* __restrict__ bbias,
    float* __restrict__ hln) {
    __shared__ __align__(16) float Whs[66 * 132];  // stride 33 float4, 34848 B
    __shared__ float ebuf[64 * 67];                // stride 67, 17152 B
    __shared__ __align__(16) float bhs[128], gs[128], bs_[128];
    int t = threadIdx.x;
    for (int gi = t; gi < 66 * 128; gi += 256) {
        int i = gi >> 7, d = gi & 127;
        Whs[i * 132 + d] = Wh[gi];
    }
    if (t < 128) { bhs[t] = bh[t]; gs[t] = g[t]; bs_[t] = bbias[t]; }
    size_t rbase = (size_t)blockIdx.x * 64;
    if (t < 192) ebuf[(t / 3) * 67 + (t % 3)] = inputs[rbase * 3 + t];
    for (int idx = t; idx < 64 * 63; idx += 256) {
        int rr = idx / 63, i = idx - rr * 63;
        ebuf[rr * 67 + 3 + i] = embed[rbase * 63 + idx];
    }
    __syncthreads();
    int tr = t >> 5, tc = t & 31;
    const float4* Whs4 = (const float4*)Whs;
    float4 b4 = *(const float4*)&bhs[tc * 4];
    float4 acc[8];
#pragma unroll
    for (int r8 = 0; r8 < 8; r8++) acc[r8] = b4;
    const float* ev = &ebuf[(tr * 8) * 67];
#pragma unroll 2
    for (int k = 0; k < 66; k++) {
        float4 w4 = Whs4[k * 33 + tc];
#pragma unroll
        for (int r8 = 0; r8 < 8; r8++) {
            float e = ev[r8 * 67 + k];
            acc[r8].x = fmaf(e, w4.x, acc[r8].x);
            acc[r8].y = fmaf(e, w4.y, acc[r8].y);
            acc[r8].z = fmaf(e, w4.z, acc[r8].z);
            acc[r8].w = fmaf(e, w4.w, acc[r8].w);
        }
    }
    // per-row LN: reduce across the 32 tc lanes (contiguous 32-lane half-wave)
    float s1[8], s2[8];
#pragma unroll
    for (int r8 = 0; r8 < 8; r8++) {
        float v = acc[r8].x + acc[r8].y + acc[r8].z + acc[r8].w;
        v += __shfl_xor(v, 1);  v += __shfl_xor(v, 2);
        v += __shfl_xor(v, 4);  v += __shfl_xor(v, 8);
        v += __shfl_xor(v, 16);
        s1[r8] = v * (1.0f / 128.0f);
    }
#pragma unroll
    for (int r8 = 0; r8 < 8; r8++) {
        float m = s1[r8];
        float ex = acc[r8].x - m, ey = acc[r8].y - m, ez = acc[r8].z - m, ew = acc[r8].w - m;
        float v = ex * ex + ey * ey + ez * ez + ew * ew;
        v += __shfl_xor(v, 1);  v += __shfl_xor(v, 2);
        v += __shfl_xor(v, 4);  v += __shfl_xor(v, 8);
        v += __shfl_xor(v, 16);
        s2[r8] = rsqrtf(v * (1.0f / 128.0f) + 1e-5f);
    }
    float4 gg = *(const float4*)&gs[tc * 4];
    float4 bb4 = *(const float4*)&bs_[tc * 4];
    float4* out4 = (float4*)hln;
#pragma unroll
    for (int r8 = 0; r8 < 8; r8++) {
        float m = s1[r8], inv = s2[r8];
        float4 o;
        o.x = fmaf((acc[r8].x - m) * inv, gg.x, bb4.x);
        o.y = fmaf((acc[r8].y - m) * inv, gg.y, bb4.y);
        o.z = fmaf((acc[r8].z - m) * inv, gg.z, bb4.z);
        o.w = fmaf((acc[r8].w - m) * inv, gg.w, bb4.w);
        out4[(rbase + tr * 8 + r8) * 32 + tc] = o;
    }
}

// ---------- K3: initial q from slots ----------

__global__ __launch_bounds__(128) void k3_q(
    const float* __restrict__ slots,
    const float* __restrict__ lnsg, const float* __restrict__ lnsb,
    const float* __restrict__ wq, const float* __restrict__ bq,
    const float* __restrict__ wkT, const float* __restrict__ bk,
    float* __restrict__ qt, float* __restrict__ qc,
    float* __restrict__ vec, float* __restrict__ den) {
    __shared__ float shA[128];
    __shared__ float red[2];
    int bs = blockIdx.x;
    float x = slots[bs * 128 + threadIdx.x];
    emit_q(x, bs, lnsg, lnsb, wq, bq, wkT, bk, qt, qc, vec, den, shA, red);
}

// ---------- K4: attention pass (LDS-tiled, single hln read) ----------
// 1024 blocks: 128/batch, each 256 rows = 4 tiles of 64. LDS 40.1KB -> 4/CU.

__global__ __launch_bounds__(256) void k4_attn(
    const float4* __restrict__ hln4, const float* __restrict__ qt,
    const float* __restrict__ qc, float* __restrict__ vec, float* __restrict__ den) {
    __shared__ __align__(16) float tile[64 * 132];  // stride 33 float4, 33792 B
    __shared__ __align__(16) float qswz[8 * 132];   // 4224 B
    __shared__ __align__(16) float alds[64 * 8];    // 2048 B
    __shared__ float qcl[8];
    int t = threadIdx.x;
    int blk = blockIdx.x;
    int b = blk >> 7;
    int slab = blk & 127;
    size_t row0 = (size_t)b * N_ + (size_t)slab * 256;
    const float4* src = hln4 + row0 * 32;
    float4* tile4 = (float4*)tile;
    const float4* tile4c = (const float4*)tile;
    const float4* qswz4 = (const float4*)qswz;

    for (int i = t; i < 1024; i += 256) {
        int s = i >> 7, d = i & 127;
        qswz[s * 132 + d] = qt[b * 1024 + i];
    }
    if (t < 8) qcl[t] = qc[b * 8 + t];

    int rr = t >> 2, qq = t & 3;          // phase-1 roles
    int so = t >> 5, c = t & 31;          // phase-2 roles
    float4 acc = {0.f, 0.f, 0.f, 0.f};
    float dden = 0.f;
    float4 st[8];
#pragma unroll
    for (int k = 0; k < 8; k++) st[k] = src[t + k * 256];
#pragma unroll
    for (int k = 0; k < 8; k++) {
        int idx = t + k * 256;
        tile4[(idx >> 5) * 33 + (idx & 31)] = st[k];
    }
    __syncthreads();

    for (int tt = 0; tt < 4; tt++) {
        if (tt < 3) {
            const float4* sp = src + (size_t)(tt + 1) * 2048;
#pragma unroll
            for (int k = 0; k < 8; k++) st[k] = sp[t + k * 256];
        }
        // ---- phase 1: dots + softmax (4 lanes per row, qq quarters) ----
        float p[8];
#pragma unroll
        for (int s = 0; s < 8; s++) p[s] = 0.f;
#pragma unroll
        for (int jj = 0; jj < 8; jj++) {
            float4 hv = tile4c[rr * 33 + qq * 8 + jj];
#pragma unroll
            for (int s = 0; s < 8; s++) {
                float4 qv = qswz4[s * 33 + qq * 8 + jj];
                p[s] = fmaf(hv.x, qv.x, p[s]);
                p[s] = fmaf(hv.y, qv.y, p[s]);
                p[s] = fmaf(hv.z, qv.z, p[s]);
                p[s] = fmaf(hv.w, qv.w, p[s]);
            }
        }
#pragma unroll
        for (int s = 0; s < 8; s++) {
            float v = p[s];
            v += __shfl_xor(v, 1);
            v += __shfl_xor(v, 2);
            p[s] = v + qcl[s];
        }
        float mx = p[0];
#pragma unroll
        for (int s = 1; s < 8; s++) mx = fmaxf(mx, p[s]);
        float sum = 0.f;
#pragma unroll
        for (int s = 0; s < 8; s++) { p[s] = __expf(p[s] - mx); sum += p[s]; }
        float invs = 1.0f / sum;
        if (qq == 0) {
            float4 a0, a1;
            a0.x = fmaf(p[0], invs, 1e-8f); a0.y = fmaf(p[1], invs, 1e-8f);
            a0.z = fmaf(p[2], invs, 1e-8f); a0.w = fmaf(p[3], invs, 1e-8f);
            a1.x = fmaf(p[4], invs, 1e-8f); a1.y = fmaf(p[5], invs, 1e-8f);
            a1.z = fmaf(p[6], invs, 1e-8f); a1.w = fmaf(p[7], invs, 1e-8f);
            *(float4*)&alds[rr * 8] = a0;
            *(float4*)&alds[rr * 8 + 4] = a1;
        }
        __syncthreads();
        // ---- phase 2: acc(s=so, quad c) += a_so(r) * h(r, quad c) ----
#pragma unroll 8
        for (int r = 0; r < 64; r++) {
            float av = alds[r * 8 + so];
            float4 hv = tile4c[r * 33 + c];
            acc.x = fmaf(av, hv.x, acc.x);
            acc.y = fmaf(av, hv.y, acc.y);
            acc.z = fmaf(av, hv.z, acc.z);
            acc.w = fmaf(av, hv.w, acc.w);
            if (c == 0) dden += av;
        }
        __syncthreads();
        if (tt < 3) {
#pragma unroll
            for (int k = 0; k < 8; k++) {
                int idx = t + k * 256;
                tile4[(idx >> 5) * 33 + (idx & 31)] = st[k];
            }
            __syncthreads();
        }
    }
    float* vp = vec + b * 1024 + so * 128 + c * 4;
    atomicAdd(vp + 0, acc.x);
    atomicAdd(vp + 1, acc.y);
    atomicAdd(vp + 2, acc.z);
    atomicAdd(vp + 3, acc.w);
    if (c == 0) atomicAdd(&den[b * 8 + so], dden);
}

// ---------- K5: updates -> GRU -> MLP -> slots (+ next q) ----------

__global__ __launch_bounds__(128) void k5_update(
    const float* __restrict__ vec, const float* __restrict__ den,
    const float* __restrict__ wv, const float* __restrict__ bv,
    const float* __restrict__ wihT, const float* __restrict__ whhT,
    const float* __restrict__ bih, const float* __restrict__ bhh,
    const float* __restrict__ lnfg, const float* __restrict__ lnfb,
    const float* __restrict__ m1w, const float* __restrict__ m1b,
    const float* __restrict__ m2w, const float* __restrict__ m2b,
    float* __restrict__ slots,
    const float* __restrict__ lnsg, const float* __restrict__ lnsb,
    const float* __restrict__ wq, const float* __restrict__ bq,
    const float* __restrict__ wkT, const float* __restrict__ bk,
    float* __restrict__ qt, float* __restrict__ qc,
    float* __restrict__ out, int compute_q, int write_out) {
    __shared__ float sA[128], sB[128], sC[128];
    __shared__ float red[2];
    int bs = blockIdx.x, t = threadIdx.x;
    float dv = den[bs];
    sA[t] = vec[bs * 128 + t] / dv;
    sC[t] = slots[bs * 128 + t];
    __syncthreads();
    float upd = bv[t];
#pragma unroll 4
    for (int i = 0; i < 128; i++) upd = fmaf(sA[i], wv[i * 128 + t], upd);
    __syncthreads();
    sB[t] = upd;
    __syncthreads();
    float gi[3], gh[3];
#pragma unroll 1
    for (int gx = 0; gx < 3; gx++) {
        int g = gx * 128 + t;
        float a = bih[g], hh = bhh[g];
#pragma unroll 4
        for (int d = 0; d < 128; d++) {
            a = fmaf(sB[d], wihT[d * 384 + g], a);
            hh = fmaf(sC[d], whhT[d * 384 + g], hh);
        }
        gi[gx] = a; gh[gx] = hh;
    }
    float rg = 1.f / (1.f + expf(-(gi[0] + gh[0])));
    float zg = 1.f / (1.f + expf(-(gi[1] + gh[1])));
    float ng = tanhf(fmaf(rg, gh[2], gi[2]));
    float hnew = (1.f - zg) * ng + zg * sC[t];
    float m = block128_sum(hnew, red) * (1.0f / 128.0f);
    float e = hnew - m;
    float var = block128_sum(e * e, red) * (1.0f / 128.0f);
    float inv = rsqrtf(var + 1e-5f);
    __syncthreads();
    sA[t] = fmaf(e * inv, lnfg[t], lnfb[t]);
    __syncthreads();
    float m1 = m1b[t];
#pragma unroll 4
    for (int i = 0; i < 128; i++) m1 = fmaf(sA[i], m1w[i * 128 + t], m1);
    __syncthreads();
    sB[t] = m1;
    __syncthreads();
    float m2 = m2b[t];
#pragma unroll 4
    for (int i = 0; i < 128; i++) m2 = fmaf(sB[i], m2w[i * 128 + t], m2);
    float snew = hnew + m2;
    slots[bs * 128 + t] = snew;
    if (write_out) out[bs * 128 + t] = snew;
    if (compute_q) {
        emit_q(snew, bs, lnsg, lnsb, wq, bq, wkT, bk, qt, qc,
               const_cast<float*>(vec), const_cast<float*>(den), sA, red);
    }
}

// ---------- launch ----------

extern "C" void kernel_launch(void* const* d_in, const int* in_sizes, int n_in,
                              void* d_out, int out_size, void* d_ws, size_t ws_size,
                              hipStream_t stream) {
    const float* inputs = (const float*)d_in[0];
    const float* embed  = (const float*)d_in[1];
    const float* mu     = (const float*)d_in[2];
    const float* sg     = (const float*)d_in[3];
    const float* w0 = (const float*)d_in[4];  const float* b0 = (const float*)d_in[5];
    const float* w1 = (const float*)d_in[6];  const float* b1 = (const float*)d_in[7];
    const float* w2 = (const float*)d_in[8];  const float* b2 = (const float*)d_in[9];
    const float* w3 = (const float*)d_in[10]; const float* b3 = (const float*)d_in[11];
    const float* w4 = (const float*)d_in[12]; const float* b4 = (const float*)d_in[13];
    const float* w5 = (const float*)d_in[14]; const float* b5 = (const float*)d_in[15];
    const float* w7 = (const float*)d_in[16]; const float* b7 = (const float*)d_in[17];
    const float* wq = (const float*)d_in[18]; const float* bq = (const float*)d_in[19];
    const float* wk = (const float*)d_in[20]; const float* bk = (const float*)d_in[21];
    const float* wv = (const float*)d_in[22]; const float* bv = (const float*)d_in[23];
    const float* ln_in_g = (const float*)d_in[24]; const float* ln_in_b = (const float*)d_in[25];
    const float* ln_sl_g = (const float*)d_in[26]; const float* ln_sl_b = (const float*)d_in[27];
    const float* ln_ff_g = (const float*)d_in[28]; const float* ln_ff_b = (const float*)d_in[29];
    const float* gwih = (const float*)d_in[30]; const float* gwhh = (const float*)d_in[31];
    const float* gbih = (const float*)d_in[32]; const float* gbhh = (const float*)d_in[33];
    const float* m1w = (const float*)d_in[34]; const float* m1b = (const float*)d_in[35];
    const float* m2w = (const float*)d_in[36]; const float* m2b = (const float*)d_in[37];

    char* ws = (char*)d_ws;
    float* hln = (float*)ws;
    size_t off = (size_t)NB_ * 128 * 4;  // 128 MB f32 hln row-major
    float* Wh    = (float*)(ws + off); off += 66 * 128 * 4;
    float* bh    = (float*)(ws + off); off += 128 * 4;
    float* slots = (float*)(ws + off); off += 64 * 128 * 4;
    float* qt    = (float*)(ws + off); off += 64 * 128 * 4;
    float* qc    = (float*)(ws + off); off += 64 * 4;
    float* vec   = (float*)(ws + off); off += 64 * 128 * 4;
    float* den   = (float*)(ws + off); off += 64 * 4;
    float* wihT  = (float*)(ws + off); off += 384 * 128 * 4;
    float* whhT  = (float*)(ws + off); off += 384 * 128 * 4;
    float* wkT   = (float*)(ws + off); off += 128 * 128 * 4;

    k0_transpose<<<448, 256, 0, stream>>>(gwih, gwhh, wk, wihT, whhT, wkT);
    k1_setup<<<1, 256, 0, stream>>>(w0, b0, w1, b1, w2, b2, w3, b3, w4, b4, w5, b5,
                                    w7, b7, mu, sg, Wh, bh, slots);
    k2_hln<<<NB_ / 64, 256, 0, stream>>>(inputs, embed, Wh, bh, ln_in_g, ln_in_b, hln);
    k3_q<<<64, 128, 0, stream>>>(slots, ln_sl_g, ln_sl_b, wq, bq, wkT, bk, qt, qc, vec, den);
    for (int it = 0; it < 3; it++) {
        k4_attn<<<1024, 256, 0, stream>>>((const float4*)hln, qt, qc, vec, den);
        k5_update<<<64, 128, 0, stream>>>(vec, den, wv, bv, wihT, whhT, gbih, gbhh,
                                          ln_ff_g, ln_ff_b, m1w, m1b, m2w, m2b, slots,
                                          ln_sl_g, ln_sl_b, wq, bq, wkT, bk, qt, qc,
                                          (float*)d_out, (it < 2) ? 1 : 0, (it == 2) ? 1 : 0);
    }
}

// Round 8
// 494.866 us; speedup vs baseline: 1.1718x; 1.1718x over previous
//
#include <hip/hip_runtime.h>

// SlotAttention fused implementation (bf16 hln, row-major).
//   - 6-layer linear stack folded into effective 66->128 affine (Wh, bh).
//   - k,v projections folded out of the N dimension:
//       q.k_n = (wk@q) . hln_n + q.bk ;  updates = (sum attn*hln)/den @ wv + bv
//   - hln = LN(h) materialized BF16 row-major [NB][128]  (64 MB, L3-resident).
//   - slot init: JAX partitionable threefry: bits[i] = o0^o1, counter (0,i).
//   - k2: 128 rows/block, thread = 8 rows x 8 cols (quads {tc, tc+16}),
//         e-reads chunked float4 (4 k at a time, 2-way broadcast).
//   - k4: stride-33 f4 tile, phase-1 interleaved quarters c4 = qq+4*jj
//         (conflict-free), bf16 global staging, 4 blocks/CU.

#define B_  8
#define N_  32768
#define NB_ (B_ * N_)   // 262144 rows
#define D_  128
#define S_  8

typedef unsigned int u32;

__device__ inline u32 bfr1(float x) {  // f32 -> bf16 (RNE)
    u32 u = __float_as_uint(x);
    return (u + 0x7FFFu + ((u >> 16) & 1u)) >> 16;
}
__device__ inline u32 bfpack(float lo, float hi) { return bfr1(lo) | (bfr1(hi) << 16); }

// threefry2x32, key = (0, 42)  (jax.random.key(42))
__device__ inline void threefry42(u32 c0, u32 c1, u32& o0, u32& o1) {
    const u32 k0 = 0u, k1 = 42u, k2 = 0x1BD11BDAu ^ 0u ^ 42u;
    const u32 ks[3] = {k0, k1, k2};
    u32 x0 = c0 + k0, x1 = c1 + k1;
    const int rA[4] = {13, 15, 26, 6}, rB[4] = {17, 29, 16, 24};
#pragma unroll
    for (int i = 0; i < 5; i++) {
#pragma unroll
        for (int k = 0; k < 4; k++) {
            int r = (i & 1) ? rB[k] : rA[k];
            x0 += x1;
            x1 = (x1 << r) | (x1 >> (32 - r));
            x1 ^= x0;
        }
        x0 += ks[(i + 1) % 3];
        x1 += ks[(i + 2) % 3] + (u32)(i + 1);
    }
    o0 = x0; o1 = x1;
}

// jax uniform(-0.99999994, 1) -> sqrt(2)*erfinv  (XLA ErfInv32 polynomial)
__device__ inline float bits_to_normal(u32 b) {
    float f = __uint_as_float((b >> 9) | 0x3f800000u) - 1.0f;  // [0,1)
    const float lo = -0.99999994f;
    float r = fmaxf(lo, f * 1.99999994f + lo);
    float w = -log1pf(-r * r);
    float p;
    if (w < 5.0f) {
        w -= 2.5f;
        p = 2.81022636e-08f;
        p = fmaf(p, w, 3.43273939e-07f);
        p = fmaf(p, w, -3.5233877e-06f);
        p = fmaf(p, w, -4.39150654e-06f);
        p = fmaf(p, w, 0.00021858087f);
        p = fmaf(p, w, -0.00125372503f);
        p = fmaf(p, w, -0.00417768164f);
        p = fmaf(p, w, 0.246640727f);
        p = fmaf(p, w, 1.50140941f);
    } else {
        w = sqrtf(w) - 3.0f;
        p = -0.000200214257f;
        p = fmaf(p, w, 0.000100950558f);
        p = fmaf(p, w, 0.00134934322f);
        p = fmaf(p, w, -0.00367342844f);
        p = fmaf(p, w, 0.00573950773f);
        p = fmaf(p, w, -0.0076224613f);
        p = fmaf(p, w, 0.00943887047f);
        p = fmaf(p, w, 1.00167406f);
        p = fmaf(p, w, 2.83297682f);
    }
    return 1.41421356f * (p * r);
}

// 128-thread block sum (2 waves), red = 2-float shared scratch
__device__ inline float block128_sum(float v, float* red) {
#pragma unroll
    for (int o = 32; o; o >>= 1) v += __shfl_down(v, o);
    __syncthreads();
    if ((threadIdx.x & 63) == 0) red[threadIdx.x >> 6] = v;
    __syncthreads();
    return red[0] + red[1];
}

// LN(slot row) -> q -> qtilde(scaled), qc(scaled); zero vec/den accumulators.
__device__ void emit_q(float x, int bs,
                       const float* lnsg, const float* lnsb,
                       const float* wq, const float* bq,
                       const float* wkT, const float* bk,
                       float* qt, float* qc, float* vec, float* den,
                       float* shA, float* red) {
    int t = threadIdx.x;
    float m = block128_sum(x, red) * (1.0f / 128.0f);
    float e = x - m;
    float var = block128_sum(e * e, red) * (1.0f / 128.0f);
    float inv = rsqrtf(var + 1e-5f);
    __syncthreads();
    shA[t] = fmaf(e * inv, lnsg[t], lnsb[t]);
    __syncthreads();
    float q = bq[t];
#pragma unroll 4
    for (int i = 0; i < 128; i++) q = fmaf(shA[i], wq[i * 128 + t], q);
    __syncthreads();
    shA[t] = q;
    __syncthreads();
    float a2 = 0.f;
#pragma unroll 4
    for (int j = 0; j < 128; j++) a2 = fmaf(wkT[j * 128 + t], shA[j], a2);
    const float scale = 0.08838834764831845f;  // 128^-0.5
    qt[bs * 128 + t] = a2 * scale;
    float pr = block128_sum(shA[t] * bk[t], red);
    if (t == 0) { qc[bs] = pr * scale; den[bs] = 0.f; }
    vec[bs * 128 + t] = 0.f;
}

// ---------- K0: transpose gru weights + wk for coalesced access ----------

__global__ __launch_bounds__(256) void k0_transpose(
    const float* __restrict__ wih, const float* __restrict__ whh,
    const float* __restrict__ wk,
    float* __restrict__ wihT, float* __restrict__ whhT, float* __restrict__ wkT) {
    int idx = blockIdx.x * 256 + threadIdx.x;
    if (idx < 49152) {
        int d = idx / 384, g = idx % 384;
        wihT[idx] = wih[g * 128 + d];
    } else if (idx < 98304) {
        int o = idx - 49152;
        int d = o / 384, g = o % 384;
        whhT[o] = whh[g * 128 + d];
    } else if (idx < 114688) {
        int o = idx - 98304;
        int j = o >> 7, tcol = o & 127;
        wkT[o] = wk[tcol * 128 + j];
    }
}

// ---------- K1: fold weights, init slots ----------

__global__ __launch_bounds__(256) void k1_setup(
    const float* __restrict__ w0, const float* __restrict__ b0,
    const float* __restrict__ w1, const float* __restrict__ b1,
    const float* __restrict__ w2, const float* __restrict__ b2,
    const float* __restrict__ w3, const float* __restrict__ b3,
    const float* __restrict__ w4, const float* __restrict__ b4,
    const float* __restrict__ w5, const float* __restrict__ b5,
    const float* __restrict__ w7, const float* __restrict__ b7,
    const float* __restrict__ mu, const float* __restrict__ sg,
    float* __restrict__ Wh, float* __restrict__ bh, float* __restrict__ slots) {
    __shared__ float A[192], Bt[96], bb[64], bb2[32];
    __shared__ float stats[2];
    int t = threadIdx.x;
    for (int i = t; i < 192; i += 256) A[i] = w0[i];
    for (int i = t; i < 64; i += 256) bb[i] = b0[i];
    __syncthreads();
    const float* wl[5] = {w1, w2, w3, w4, w5};
    const float* bl[5] = {b1, b2, b3, b4, b5};
    int kin = 64;
    for (int l = 0; l < 5; l++) {
        const float* w = wl[l];
        const float* bias = bl[l];
        if (t < 96) {
            int i = t / 32, j = t % 32;
            float acc = 0.f;
            for (int k = 0; k < kin; k++) acc += A[i * kin + k] * w[k * 32 + j];
            Bt[i * 32 + j] = acc;
        } else if (t < 128) {
            int j = t - 96;
            float acc = bias[j];
            for (int k = 0; k < kin; k++) acc += bb[k] * w[k * 32 + j];
            bb2[j] = acc;
        }
        __syncthreads();
        if (t < 96) A[t] = Bt[t];
        if (t < 32) bb[t] = bb2[t];
        __syncthreads();
        kin = 32;
    }
    for (int idx = t; idx < 66 * 128; idx += 256) {
        int i = idx >> 7, j = idx & 127;
        float acc = w7[idx];
        if (i < 3) {
            for (int k = 0; k < 32; k++) acc += A[i * 32 + k] * w7[(66 + k) * 128 + j];
        }
        Wh[idx] = acc;
    }
    for (int j = t; j < 128; j += 256) {
        float acc = b7[j];
        for (int k = 0; k < 32; k++) acc += bb[k] * w7[(66 + k) * 128 + j];
        bh[j] = acc;
    }
    if (t == 0) {
        float s1 = 0.f, s2 = 0.f;
        for (int d = 0; d < 128; d++) { s1 += mu[d]; s2 += sg[d]; }
        float mmu = s1 / 128.f, msg = s2 / 128.f;
        float ss = 0.f;
        for (int d = 0; d < 128; d++) { float e = sg[d] - msg; ss += e * e; }
        stats[0] = mmu;
        stats[1] = sqrtf(64.f * ss / 8191.f);  // std over broadcast 8192, ddof=1
    }
    __syncthreads();
    float mean = stats[0], sd = stats[1];
    for (int p = t; p < 8192; p += 256) {
        u32 o0, o1;
        threefry42(0u, (u32)p, o0, o1);
        slots[p] = fmaf(sd, bits_to_normal(o0 ^ o1), mean);
    }
}

// ---------- K2: build hln (bf16 row-major [NB][128]) ----------
// 128 rows/block; thread (tr 0-15, tc 0-15): rows tr*8..+7, f4-col quads {tc, tc+16}.

__global__ __launch_bounds__(256) void k2_hln(
    const float* __restrict__ inputs, const float* __restrict__ embed,
    const float* __restrict__ Wh, const float* __restrict__ bh,
    const float* __restrict__ g, const float* __restrict__ bbias,
    uint2* __restrict__ hlnb) {
    __shared__ __align__(16) float Whs[66 * 132];   // 34848 B (stride 33 f4)
    __shared__ __align__(16) float ebuf[128 * 68];  // 34816 B (stride 17 f4)
    __shared__ __align__(16) float bhs[128], gs[128], bs_[128];
    int t = threadIdx.x;
    for (int gi = t; gi < 66 * 128; gi += 256) {
        int i = gi >> 7, d = gi & 127;
        Whs[i * 132 + d] = Wh[gi];
    }
    if (t < 128) { bhs[t] = bh[t]; gs[t] = g[t]; bs_[t] = bbias[t]; }
    size_t rbase = (size_t)blockIdx.x * 128;
    for (int idx = t; idx < 384; idx += 256)
        ebuf[(idx / 3) * 68 + (idx % 3)] = inputs[rbase * 3 + idx];
    for (int idx = t; idx < 128 * 63; idx += 256) {
        int rr = idx / 63, i = idx - rr * 63;
        ebuf[rr * 68 + 3 + i] = embed[rbase * 63 + idx];
    }
    __syncthreads();
    int tr = t >> 4, tc = t & 15;
    const float4* Whs4 = (const float4*)Whs;
    const float4* ebuf4 = (const float4*)ebuf;
    float4 acc0[8], acc1[8];
    float4 b40 = *(const float4*)&bhs[tc * 4];
    float4 b41 = *(const float4*)&bhs[64 + tc * 4];
#pragma unroll
    for (int r8 = 0; r8 < 8; r8++) { acc0[r8] = b40; acc1[r8] = b41; }
#pragma unroll 2
    for (int kc = 0; kc < 16; kc++) {
        float4 e4[8];
#pragma unroll
        for (int r8 = 0; r8 < 8; r8++) e4[r8] = ebuf4[(tr * 8 + r8) * 17 + kc];
        float4 w0[4], w1[4];
#pragma unroll
        for (int kk = 0; kk < 4; kk++) {
            w0[kk] = Whs4[(kc * 4 + kk) * 33 + tc];
            w1[kk] = Whs4[(kc * 4 + kk) * 33 + 16 + tc];
        }
#pragma unroll
        for (int r8 = 0; r8 < 8; r8++) {
            float4 e = e4[r8];
            acc0[r8].x = fmaf(e.x, w0[0].x, acc0[r8].x); acc0[r8].y = fmaf(e.x, w0[0].y, acc0[r8].y);
            acc0[r8].z = fmaf(e.x, w0[0].z, acc0[r8].z); acc0[r8].w = fmaf(e.x, w0[0].w, acc0[r8].w);
            acc1[r8].x = fmaf(e.x, w1[0].x, acc1[r8].x); acc1[r8].y = fmaf(e.x, w1[0].y, acc1[r8].y);
            acc1[r8].z = fmaf(e.x, w1[0].z, acc1[r8].z); acc1[r8].w = fmaf(e.x, w1[0].w, acc1[r8].w);
            acc0[r8].x = fmaf(e.y, w0[1].x, acc0[r8].x); acc0[r8].y = fmaf(e.y, w0[1].y, acc0[r8].y);
            acc0[r8].z = fmaf(e.y, w0[1].z, acc0[r8].z); acc0[r8].w = fmaf(e.y, w0[1].w, acc0[r8].w);
            acc1[r8].x = fmaf(e.y, w1[1].x, acc1[r8].x); acc1[r8].y = fmaf(e.y, w1[1].y, acc1[r8].y);
            acc1[r8].z = fmaf(e.y, w1[1].z, acc1[r8].z); acc1[r8].w = fmaf(e.y, w1[1].w, acc1[r8].w);
            acc0[r8].x = fmaf(e.z, w0[2].x, acc0[r8].x); acc0[r8].y = fmaf(e.z, w0[2].y, acc0[r8].y);
            acc0[r8].z = fmaf(e.z, w0[2].z, acc0[r8].z); acc0[r8].w = fmaf(e.z, w0[2].w, acc0[r8].w);
            acc1[r8].x = fmaf(e.z, w1[2].x, acc1[r8].x); acc1[r8].y = fmaf(e.z, w1[2].y, acc1[r8].y);
            acc1[r8].z = fmaf(e.z, w1[2].z, acc1[r8].z); acc1[r8].w = fmaf(e.z, w1[2].w, acc1[r8].w);
            acc0[r8].x = fmaf(e.w, w0[3].x, acc0[r8].x); acc0[r8].y = fmaf(e.w, w0[3].y, acc0[r8].y);
            acc0[r8].z = fmaf(e.w, w0[3].z, acc0[r8].z); acc0[r8].w = fmaf(e.w, w0[3].w, acc0[r8].w);
            acc1[r8].x = fmaf(e.w, w1[3].x, acc1[r8].x); acc1[r8].y = fmaf(e.w, w1[3].y, acc1[r8].y);
            acc1[r8].z = fmaf(e.w, w1[3].z, acc1[r8].z); acc1[r8].w = fmaf(e.w, w1[3].w, acc1[r8].w);
        }
    }
    // tail k = 64, 65
#pragma unroll
    for (int k = 64; k < 66; k++) {
        float4 w0t = Whs4[k * 33 + tc];
        float4 w1t = Whs4[k * 33 + 16 + tc];
#pragma unroll
        for (int r8 = 0; r8 < 8; r8++) {
            float e = ebuf[(tr * 8 + r8) * 68 + k];
            acc0[r8].x = fmaf(e, w0t.x, acc0[r8].x); acc0[r8].y = fmaf(e, w0t.y, acc0[r8].y);
            acc0[r8].z = fmaf(e, w0t.z, acc0[r8].z); acc0[r8].w = fmaf(e, w0t.w, acc0[r8].w);
            acc1[r8].x = fmaf(e, w1t.x, acc1[r8].x); acc1[r8].y = fmaf(e, w1t.y, acc1[r8].y);
            acc1[r8].z = fmaf(e, w1t.z, acc1[r8].z); acc1[r8].w = fmaf(e, w1t.w, acc1[r8].w);
        }
    }
    // per-row LN across the 16 tc lanes (consecutive lane ids within tr group)
    float4 gg0 = *(const float4*)&gs[tc * 4];
    float4 gg1 = *(const float4*)&gs[64 + tc * 4];
    float4 bb0 = *(const float4*)&bs_[tc * 4];
    float4 bb1 = *(const float4*)&bs_[64 + tc * 4];
#pragma unroll
    for (int r8 = 0; r8 < 8; r8++) {
        float v = acc0[r8].x + acc0[r8].y + acc0[r8].z + acc0[r8].w
                + acc1[r8].x + acc1[r8].y + acc1[r8].z + acc1[r8].w;
        v += __shfl_xor(v, 1); v += __shfl_xor(v, 2);
        v += __shfl_xor(v, 4); v += __shfl_xor(v, 8);
        float m = v * (1.0f / 128.0f);
        float e0x = acc0[r8].x - m, e0y = acc0[r8].y - m, e0z = acc0[r8].z - m, e0w = acc0[r8].w - m;
        float e1x = acc1[r8].x - m, e1y = acc1[r8].y - m, e1z = acc1[r8].z - m, e1w = acc1[r8].w - m;
        float s2 = e0x * e0x + e0y * e0y + e0z * e0z + e0w * e0w
                 + e1x * e1x + e1y * e1y + e1z * e1z + e1w * e1w;
        s2 += __shfl_xor(s2, 1); s2 += __shfl_xor(s2, 2);
        s2 += __shfl_xor(s2, 4); s2 += __shfl_xor(s2, 8);
        float inv = rsqrtf(s2 * (1.0f / 128.0f) + 1e-5f);
        float f0x = fmaf(e0x * inv, gg0.x, bb0.x), f0y = fmaf(e0y * inv, gg0.y, bb0.y);
        float f0z = fmaf(e0z * inv, gg0.z, bb0.z), f0w = fmaf(e0w * inv, gg0.w, bb0.w);
        float f1x = fmaf(e1x * inv, gg1.x, bb1.x), f1y = fmaf(e1y * inv, gg1.y, bb1.y);
        float f1z = fmaf(e1z * inv, gg1.z, bb1.z), f1w = fmaf(e1w * inv, gg1.w, bb1.w);
        size_t row = rbase + tr * 8 + r8;
        uint2 o0; o0.x = bfpack(f0x, f0y); o0.y = bfpack(f0z, f0w);
        uint2 o1; o1.x = bfpack(f1x, f1y); o1.y = bfpack(f1z, f1w);
        hlnb[row * 32 + tc] = o0;
        hlnb[row * 32 + 16 + tc] = o1;
    }
}

// ---------- K3: initial q from slots ----------

__global__ __launch_bounds__(128) void k3_q(
    const float* __restrict__ slots,
    const float* __restrict__ lnsg, const float* __restrict__ lnsb,
    const float* __restrict__ wq, const float* __restrict__ bq,
    const float* __restrict__ wkT, const float* __restrict__ bk,
    float* __restrict__ qt, float* __restrict__ qc,
    float* __restrict__ vec, float* __restrict__ den) {
    __shared__ float shA[128];
    __shared__ float red[2];
    int bs = blockIdx.x;
    float x = slots[bs * 128 + threadIdx.x];
    emit_q(x, bs, lnsg, lnsb, wq, bq, wkT, bk, qt, qc, vec, den, shA, red);
}

// ---------- K4: attention pass (bf16 global, f32 LDS tile) ----------
// 1024 blocks: 128/batch, each 256 rows = 4 tiles of 64. LDS 40.1KB -> 4/CU.

__global__ __launch_bounds__(256) void k4_attn(
    const uint4* __restrict__ hlnb4, const float* __restrict__ qt,
    const float* __restrict__ qc, float* __restrict__ vec, float* __restrict__ den) {
    __shared__ __align__(16) float tile[64 * 132];  // stride 33 f4, 33792 B
    __shared__ __align__(16) float qswz[8 * 132];   // 4224 B
    __shared__ __align__(16) float alds[64 * 8];    // 2048 B
    __shared__ float qcl[8];
    int t = threadIdx.x;
    int blk = blockIdx.x;
    int b = blk >> 7;
    int slab = blk & 127;
    size_t row0 = (size_t)b * N_ + (size_t)slab * 256;
    const uint4* src = hlnb4 + row0 * 16;   // 16 uint4 (128 bf16) per row
    float4* tile4 = (float4*)tile;
    const float4* tile4c = (const float4*)tile;
    const float4* qswz4 = (const float4*)qswz;

    for (int i = t; i < 1024; i += 256) {
        int s = i >> 7, d = i & 127;
        qswz[s * 132 + d] = qt[b * 1024 + i];
    }
    if (t < 8) qcl[t] = qc[b * 8 + t];

    int rr = t >> 2, qq = t & 3;          // phase-1 roles
    int so = t >> 5, c = t & 31;          // phase-2 roles
    float4 acc = {0.f, 0.f, 0.f, 0.f};
    float dden = 0.f;
    uint4 st[4];
#pragma unroll
    for (int k = 0; k < 4; k++) st[k] = src[t + k * 256];
#pragma unroll
    for (int k = 0; k < 4; k++) {
        int idx = t + k * 256;
        int row = idx >> 4, c8 = idx & 15;
        uint4 u = st[k];
        float4 lo, hi;
        lo.x = __uint_as_float(u.x << 16); lo.y = __uint_as_float(u.x & 0xFFFF0000u);
        lo.z = __uint_as_float(u.y << 16); lo.w = __uint_as_float(u.y & 0xFFFF0000u);
        hi.x = __uint_as_float(u.z << 16); hi.y = __uint_as_float(u.z & 0xFFFF0000u);
        hi.z = __uint_as_float(u.w << 16); hi.w = __uint_as_float(u.w & 0xFFFF0000u);
        tile4[row * 33 + c8 * 2] = lo;
        tile4[row * 33 + c8 * 2 + 1] = hi;
    }
    __syncthreads();

    for (int tt = 0; tt < 4; tt++) {
        if (tt < 3) {
            const uint4* sp = src + (size_t)(tt + 1) * 1024;
#pragma unroll
            for (int k = 0; k < 4; k++) st[k] = sp[t + k * 256];
        }
        // ---- phase 1: dots + softmax; 4 lanes/row, interleaved quarters ----
        float p[8];
#pragma unroll
        for (int s = 0; s < 8; s++) p[s] = 0.f;
#pragma unroll
        for (int jj = 0; jj < 8; jj++) {
            int c4 = qq + 4 * jj;
            float4 hv = tile4c[rr * 33 + c4];
#pragma unroll
            for (int s = 0; s < 8; s++) {
                float4 qv = qswz4[s * 33 + c4];
                p[s] = fmaf(hv.x, qv.x, p[s]);
                p[s] = fmaf(hv.y, qv.y, p[s]);
                p[s] = fmaf(hv.z, qv.z, p[s]);
                p[s] = fmaf(hv.w, qv.w, p[s]);
            }
        }
#pragma unroll
        for (int s = 0; s < 8; s++) {
            float v = p[s];
            v += __shfl_xor(v, 1);
            v += __shfl_xor(v, 2);
            p[s] = v + qcl[s];
        }
        float mx = p[0];
#pragma unroll
        for (int s = 1; s < 8; s++) mx = fmaxf(mx, p[s]);
        float sum = 0.f;
#pragma unroll
        for (int s = 0; s < 8; s++) { p[s] = __expf(p[s] - mx); sum += p[s]; }
        float invs = 1.0f / sum;
        if (qq == 0) {
            float4 a0, a1;
            a0.x = fmaf(p[0], invs, 1e-8f); a0.y = fmaf(p[1], invs, 1e-8f);
            a0.z = fmaf(p[2], invs, 1e-8f); a0.w = fmaf(p[3], invs, 1e-8f);
            a1.x = fmaf(p[4], invs, 1e-8f); a1.y = fmaf(p[5], invs, 1e-8f);
            a1.z = fmaf(p[6], invs, 1e-8f); a1.w = fmaf(p[7], invs, 1e-8f);
            *(float4*)&alds[rr * 8] = a0;
            *(float4*)&alds[rr * 8 + 4] = a1;
        }
        __syncthreads();
        // ---- phase 2: acc(s=so, quad c) += a_so(r) * h(r, quad c) ----
#pragma unroll 8
        for (int r = 0; r < 64; r++) {
            float av = alds[r * 8 + so];
            float4 hv = tile4c[r * 33 + c];
            acc.x = fmaf(av, hv.x, acc.x);
            acc.y = fmaf(av, hv.y, acc.y);
            acc.z = fmaf(av, hv.z, acc.z);
            acc.w = fmaf(av, hv.w, acc.w);
            if (c == 0) dden += av;
        }
        __syncthreads();
        if (tt < 3) {
#pragma unroll
            for (int k = 0; k < 4; k++) {
                int idx = t + k * 256;
                int row = idx >> 4, c8 = idx & 15;
                uint4 u = st[k];
                float4 lo, hi;
                lo.x = __uint_as_float(u.x << 16); lo.y = __uint_as_float(u.x & 0xFFFF0000u);
                lo.z = __uint_as_float(u.y << 16); lo.w = __uint_as_float(u.y & 0xFFFF0000u);
                hi.x = __uint_as_float(u.z << 16); hi.y = __uint_as_float(u.z & 0xFFFF0000u);
                hi.z = __uint_as_float(u.w << 16); hi.w = __uint_as_float(u.w & 0xFFFF0000u);
                tile4[row * 33 + c8 * 2] = lo;
                tile4[row * 33 + c8 * 2 + 1] = hi;
            }
            __syncthreads();
        }
    }
    float* vp = vec + b * 1024 + so * 128 + c * 4;
    atomicAdd(vp + 0, acc.x);
    atomicAdd(vp + 1, acc.y);
    atomicAdd(vp + 2, acc.z);
    atomicAdd(vp + 3, acc.w);
    if (c == 0) atomicAdd(&den[b * 8 + so], dden);
}

// ---------- K5: updates -> GRU -> MLP -> slots (+ next q) ----------

__global__ __launch_bounds__(128) void k5_update(
    const float* __restrict__ vec, const float* __restrict__ den,
    const float* __restrict__ wv, const float* __restrict__ bv,
    const float* __restrict__ wihT, const float* __restrict__ whhT,
    const float* __restrict__ bih, const float* __restrict__ bhh,
    const float* __restrict__ lnfg, const float* __restrict__ lnfb,
    const float* __restrict__ m1w, const float* __restrict__ m1b,
    const float* __restrict__ m2w, const float* __restrict__ m2b,
    float* __restrict__ slots,
    const float* __restrict__ lnsg, const float* __restrict__ lnsb,
    const float* __restrict__ wq, const float* __restrict__ bq,
    const float* __restrict__ wkT, const float* __restrict__ bk,
    float* __restrict__ qt, float* __restrict__ qc,
    float* __restrict__ out, int compute_q, int write_out) {
    __shared__ float sA[128], sB[128], sC[128];
    __shared__ float red[2];
    int bs = blockIdx.x, t = threadIdx.x;
    float dv = den[bs];
    sA[t] = vec[bs * 128 + t] / dv;
    sC[t] = slots[bs * 128 + t];
    __syncthreads();
    float upd = bv[t];
#pragma unroll 4
    for (int i = 0; i < 128; i++) upd = fmaf(sA[i], wv[i * 128 + t], upd);
    __syncthreads();
    sB[t] = upd;
    __syncthreads();
    float gi[3], gh[3];
#pragma unroll 1
    for (int gx = 0; gx < 3; gx++) {
        int g = gx * 128 + t;
        float a = bih[g], hh = bhh[g];
#pragma unroll 4
        for (int d = 0; d < 128; d++) {
            a = fmaf(sB[d], wihT[d * 384 + g], a);
            hh = fmaf(sC[d], whhT[d * 384 + g], hh);
        }
        gi[gx] = a; gh[gx] = hh;
    }
    float rg = 1.f / (1.f + expf(-(gi[0] + gh[0])));
    float zg = 1.f / (1.f + expf(-(gi[1] + gh[1])));
    float ng = tanhf(fmaf(rg, gh[2], gi[2]));
    float hnew = (1.f - zg) * ng + zg * sC[t];
    float m = block128_sum(hnew, red) * (1.0f / 128.0f);
    float e = hnew - m;
    float var = block128_sum(e * e, red) * (1.0f / 128.0f);
    float inv = rsqrtf(var + 1e-5f);
    __syncthreads();
    sA[t] = fmaf(e * inv, lnfg[t], lnfb[t]);
    __syncthreads();
    float m1 = m1b[t];
#pragma unroll 4
    for (int i = 0; i < 128; i++) m1 = fmaf(sA[i], m1w[i * 128 + t], m1);
    __syncthreads();
    sB[t] = m1;
    __syncthreads();
    float m2 = m2b[t];
#pragma unroll 4
    for (int i = 0; i < 128; i++) m2 = fmaf(sB[i], m2w[i * 128 + t], m2);
    float snew = hnew + m2;
    slots[bs * 128 + t] = snew;
    if (write_out) out[bs * 128 + t] = snew;
    if (compute_q) {
        emit_q(snew, bs, lnsg, lnsb, wq, bq, wkT, bk, qt, qc,
               const_cast<float*>(vec), const_cast<float*>(den), sA, red);
    }
}

// ---------- launch ----------

extern "C" void kernel_launch(void* const* d_in, const int* in_sizes, int n_in,
                              void* d_out, int out_size, void* d_ws, size_t ws_size,
                              hipStream_t stream) {
    const float* inputs = (const float*)d_in[0];
    const float* embed  = (const float*)d_in[1];
    const float* mu     = (const float*)d_in[2];
    const float* sg     = (const float*)d_in[3];
    const float* w0 = (const float*)d_in[4];  const float* b0 = (const float*)d_in[5];
    const float* w1 = (const float*)d_in[6];  const float* b1 = (const float*)d_in[7];
    const float* w2 = (const float*)d_in[8];  const float* b2 = (const float*)d_in[9];
    const float* w3 = (const float*)d_in[10]; const float* b3 = (const float*)d_in[11];
    const float* w4 = (const float*)d_in[12]; const float* b4 = (const float*)d_in[13];
    const float* w5 = (const float*)d_in[14]; const float* b5 = (const float*)d_in[15];
    const float* w7 = (const float*)d_in[16]; const float* b7 = (const float*)d_in[17];
    const float* wq = (const float*)d_in[18]; const float* bq = (const float*)d_in[19];
    const float* wk = (const float*)d_in[20]; const float* bk = (const float*)d_in[21];
    const float* wv = (const float*)d_in[22]; const float* bv = (const float*)d_in[23];
    const float* ln_in_g = (const float*)d_in[24]; const float* ln_in_b = (const float*)d_in[25];
    const float* ln_sl_g = (const float*)d_in[26]; const float* ln_sl_b = (const float*)d_in[27];
    const float* ln_ff_g = (const float*)d_in[28]; const float* ln_ff_b = (const float*)d_in[29];
    const float* gwih = (const float*)d_in[30]; const float* gwhh = (const float*)d_in[31];
    const float* gbih = (const float*)d_in[32]; const float* gbhh = (const float*)d_in[33];
    const float* m1w = (const float*)d_in[34]; const float* m1b = (const float*)d_in[35];
    const float* m2w = (const float*)d_in[36]; const float* m2b = (const float*)d_in[37];

    char* ws = (char*)d_ws;
    uint2* hlnb = (uint2*)ws;
    size_t off = (size_t)NB_ * 128 * 2;  // 64 MB bf16 hln row-major
    float* Wh    = (float*)(ws + off); off += 66 * 128 * 4;
    float* bh    = (float*)(ws + off); off += 128 * 4;
    float* slots = (float*)(ws + off); off += 64 * 128 * 4;
    float* qt    = (float*)(ws + off); off += 64 * 128 * 4;
    float* qc    = (float*)(ws + off); off += 64 * 4;
    float* vec   = (float*)(ws + off); off += 64 * 128 * 4;
    float* den   = (float*)(ws + off); off += 64 * 4;
    float* wihT  = (float*)(ws + off); off += 384 * 128 * 4;
    float* whhT  = (float*)(ws + off); off += 384 * 128 * 4;
    float* wkT   = (float*)(ws + off); off += 128 * 128 * 4;

    k0_transpose<<<448, 256, 0, stream>>>(gwih, gwhh, wk, wihT, whhT, wkT);
    k1_setup<<<1, 256, 0, stream>>>(w0, b0, w1, b1, w2, b2, w3, b3, w4, b4, w5, b5,
                                    w7, b7, mu, sg, Wh, bh, slots);
    k2_hln<<<NB_ / 128, 256, 0, stream>>>(inputs, embed, Wh, bh, ln_in_g, ln_in_b, hlnb);
    k3_q<<<64, 128, 0, stream>>>(slots, ln_sl_g, ln_sl_b, wq, bq, wkT, bk, qt, qc, vec, den);
    for (int it = 0; it < 3; it++) {
        k4_attn<<<1024, 256, 0, stream>>>((const uint4*)hlnb, qt, qc, vec, den);
        k5_update<<<64, 128, 0, stream>>>(vec, den, wv, bv, wihT, whhT, gbih, gbhh,
                                          ln_ff_g, ln_ff_b, m1w, m1b, m2w, m2b, slots,
                                          ln_sl_g, ln_sl_b, wq, bq, wkT, bk, qt, qc,
                                          (float*)d_out, (it < 2) ? 1 : 0, (it == 2) ? 1 : 0);
    }
}